// Round 11
// baseline (3573.896 us; speedup 1.0000x reference)
//
#include <hip/hip_runtime.h>
#include <math.h>

#define B64 64
#define H 1024
#define DD 8
#define ENC 96
#define HOR 336
#define TT 432
#define NSTEP 431
#define NBLK 256
#define KS0 32      // K=1024 in 32-wide chunks
#define KS1 64      // K=2048

typedef __attribute__((ext_vector_type(8))) short short8;
typedef __attribute__((ext_vector_type(4))) float f32x4;
typedef unsigned long long ull;

__device__ __forceinline__ unsigned short f2bf(float x) {
    union { float f; unsigned u; } v; v.f = x;
    unsigned r = v.u + 0x7fffu + ((v.u >> 16) & 1u);
    return (unsigned short)(r >> 16);
}
__device__ __forceinline__ float sigm(float x) {
    return __builtin_amdgcn_rcpf(1.0f + __expf(-x));
}
__device__ __forceinline__ float ftanh(float x) {
    float e = __expf(fminf(x, 10.0f) * 2.0f);   // clamp: avoid inf/inf
    return (e - 1.0f) * __builtin_amdgcn_rcpf(e + 1.0f);
}

// Agent-coherent (sc0 sc1, MALL-coherent, no cache-maintenance) accessors
__device__ __forceinline__ short8 cload(const unsigned short* p) {
    const ull* q = (const ull*)p;
    ull lo = __hip_atomic_load(q,     __ATOMIC_RELAXED, __HIP_MEMORY_SCOPE_AGENT);
    ull hi = __hip_atomic_load(q + 1, __ATOMIC_RELAXED, __HIP_MEMORY_SCOPE_AGENT);
    union { ull u[2]; short8 s; } v; v.u[0] = lo; v.u[1] = hi;
    return v.s;
}
__device__ __forceinline__ void cstore8(ull* p, ull v) {
    __hip_atomic_store(p, v, __ATOMIC_RELAXED, __HIP_MEMORY_SCOPE_AGENT);
}

// ---------------- prep kernels (verified) ----------------

__global__ void zero_k(unsigned int* __restrict__ p, int n) {
    for (int i = blockIdx.x * 256 + threadIdx.x; i < n; i += gridDim.x * 256) p[i] = 0u;
}

__global__ void pack0_k(const float* __restrict__ w, unsigned short* __restrict__ dst) {
    const int total = 128 * 2 * KS0 * 64 * 8;
    for (int idx = blockIdx.x * 256 + threadIdx.x; idx < total; idx += gridDim.x * 256) {
        int j = idx & 7, lane = (idx >> 3) & 63, ks = (idx >> 9) & 31, nt = (idx >> 14) & 1, nb = idx >> 15;
        int rr = nt * 16 + (lane & 15);
        int row = nb * 8 + (rr >> 2) + 1024 * (rr & 3);
        int k = ks * 32 + ((lane >> 4) << 3) + j;
        dst[idx] = f2bf(w[row * 1024 + k]);
    }
}

__global__ void pack1_k(const float* __restrict__ wih, const float* __restrict__ whh,
                        unsigned short* __restrict__ dst) {
    const int total = 128 * 2 * KS1 * 64 * 8;
    for (int idx = blockIdx.x * 256 + threadIdx.x; idx < total; idx += gridDim.x * 256) {
        int j = idx & 7, lane = (idx >> 3) & 63, ks = (idx >> 9) & 63, nt = (idx >> 15) & 1, nb = idx >> 16;
        int rr = nt * 16 + (lane & 15);
        int row = nb * 8 + (rr >> 2) + 1024 * (rr & 3);
        int k = ks * 32 + ((lane >> 4) << 3) + j;
        float v = (k < 1024) ? wih[row * 1024 + k] : whh[row * 1024 + (k - 1024)];
        dst[idx] = f2bf(v);
    }
}

__global__ void pack2_k(const float* __restrict__ w, unsigned short* __restrict__ dst) {
    const int total = 2 * KS0 * 64 * 8;
    for (int idx = blockIdx.x * 256 + threadIdx.x; idx < total; idx += gridDim.x * 256) {
        int j = idx & 7, lane = (idx >> 3) & 63, ks = (idx >> 9) & 31, nt = (idx >> 14) & 1;
        int rr = nt * 16 + (lane & 15);
        int row = (rr >> 2) + 8 * (rr & 3);
        int k = ks * 32 + ((lane >> 4) << 3) + j;
        dst[idx] = f2bf(w[row * 1024 + k]);
    }
}

__global__ void copy_y_k(const float* __restrict__ inp, float* __restrict__ y) {
    const int total = B64 * HOR * DD;
    for (int i = blockIdx.x * 256 + threadIdx.x; i < total; i += gridDim.x * 256) {
        int b = i / (HOR * DD);
        int rem = i - b * (HOR * DD);
        y[i] = inp[b * (TT * DD) + ENC * DD + rem];
    }
}

__global__ void loss_k(const float* __restrict__ pred, const float* __restrict__ y,
                       float* __restrict__ loss) {
    __shared__ float part[256];
    int tid = threadIdx.x;
    int dd = tid & 7, cc = tid >> 3;
    float s = 0.f;
    for (int i = cc; i < B64 * HOR; i += 32) {
        float d = pred[i * 8 + dd] - y[i * 8 + dd];
        s += d * d;
    }
    part[tid] = s;
    __syncthreads();
    if (tid < 8) {
        float t = 0.f;
        for (int r = 0; r < 32; ++r) t += part[r * 8 + tid];
        loss[tid] = t / (float)(B64 * HOR);
    }
}

// ---- split-phase grid barrier (round-10, verified) ----
__device__ __forceinline__ void gbar_arrive(unsigned* dom, int rb, unsigned ep) {
    if (threadIdx.x == 0) {
        __builtin_amdgcn_s_waitcnt(0x0f70);     // vmcnt(0): wave-0 publish drained
        __hip_atomic_store(dom + rb * 32, ep, __ATOMIC_RELAXED,
                           __HIP_MEMORY_SCOPE_SYSTEM);
    }
}
__device__ __forceinline__ void gbar_wait(unsigned* dom, unsigned ep) {
    const int tid = threadIdx.x;
    if (tid < 64) {
        const unsigned* f0 = dom + tid * 32;
        const unsigned* f1 = dom + (tid + 64) * 32;
        for (;;) {
            unsigned a = __hip_atomic_load(f0, __ATOMIC_RELAXED, __HIP_MEMORY_SCOPE_SYSTEM);
            unsigned b = __hip_atomic_load(f1, __ATOMIC_RELAXED, __HIP_MEMORY_SCOPE_SYSTEM);
            if (__all((a >= ep) && (b >= ep))) break;
        }
    }
    __syncthreads();
}

// ---------------- persistent recurrence kernel ----------------
// Split-phase pipeline; window B has an encoder fast path (x from inp, so
// P1-cell+publish+arrive run first and P3 moves into the post-arrive gap).
__global__ __launch_bounds__(256, 1) void persist_k(
    const unsigned short* __restrict__ Wp0,
    const unsigned short* __restrict__ Wp1,
    const unsigned short* __restrict__ Wp2,
    const float* __restrict__ wih0, const float* __restrict__ b0v,
    const float* __restrict__ b1v,
    const float* __restrict__ whh2, const float* __restrict__ b2v,
    const float* __restrict__ inp,
    unsigned short* __restrict__ H0a, unsigned short* __restrict__ H0b,
    unsigned short* __restrict__ H1a, unsigned short* __restrict__ H1b,
    unsigned* __restrict__ bar0, float* __restrict__ pred)
{
    const int tid = threadIdx.x;
    const int wv = tid >> 6, lane = tid & 63;
    const int blk = blockIdx.x;
    const int bg = blk & 1, rb = blk >> 1;
    const int bl = tid & 31, u = tid >> 5;
    const int mtl = bl >> 4, m16 = bl & 15;
    unsigned* dom = bar0 + (bg << 13);      // 32KB per barrier domain

    __shared__ float red1[16 * 272];        // 17KB (P2 then P3)
    __shared__ float red2[16 * 272];        // 17KB (P1, crosses barrier B)
    __shared__ float h2x[32 * 9];
    __shared__ ull hstage[32][2];

    for (int i = tid; i < 32 * 9; i += 256) h2x[i] = 0.f;

    // ---- resident weights (all four sets; ~300 VGPR, fine at 1 blk/CU) ----
    short8 Wr0[2][8], Wr1h0[2][8], Wr1h1[2][8], Wr2[2][8];
    {
        const short8* p0 = (const short8*)Wp0;
        const short8* p1 = (const short8*)Wp1;
        const short8* p2 = (const short8*)Wp2;
        #pragma unroll
        for (int ot = 0; ot < 2; ++ot)
            #pragma unroll
            for (int kk = 0; kk < 8; ++kk) {
                Wr0[ot][kk]   = p0[((rb * 2 + ot) * KS0 + 8 * wv + kk) * 64 + lane];
                Wr1h0[ot][kk] = p1[((rb * 2 + ot) * KS1 + 8 * wv + kk) * 64 + lane];
                Wr1h1[ot][kk] = p1[((rb * 2 + ot) * KS1 + 32 + 8 * wv + kk) * 64 + lane];
                Wr2[ot][kk]   = p2[(ot * KS0 + 8 * wv + kk) * 64 + lane];
            }
    }
    float wih0r[4][8], whh2r[4][8], b0r[4], b1r[4], b2r[4];
    #pragma unroll
    for (int g = 0; g < 4; ++g) {
        int row = rb * 8 + u + 1024 * g;
        #pragma unroll
        for (int d = 0; d < 8; ++d) wih0r[g][d] = wih0[row * 8 + d];
        b0r[g] = b0v[row];
        b1r[g] = b1v[row];
        int row2 = u + 8 * g;
        #pragma unroll
        for (int d = 0; d < 8; ++d) whh2r[g][d] = whh2[row2 * 8 + d];
        b2r[g] = b2v[row2];
    }
    float c0r = 0.f, c1r = 0.f, c2r = 0.f;
    unsigned ep = 0;

    auto redWrite = [&](float* red, f32x4 (&acc)[2][2]) {
        #pragma unroll
        for (int m = 0; m < 2; ++m)
            #pragma unroll
            for (int ot = 0; ot < 2; ++ot) {
                int base = ((wv * 2 + m) * 2 + ot) * 272 + (lane & 15) * 17 + (lane >> 4) * 4;
                #pragma unroll
                for (int r = 0; r < 4; ++r) red[base + r] = acc[m][ot][r];
            }
    };
    auto redSum = [&](const float* red, int g) {
        int rr = u * 4 + g, ot = rr >> 4, rr16 = rr & 15;
        float s = 0.f;
        #pragma unroll
        for (int w2 = 0; w2 < 4; ++w2)
            s += red[((w2 * 2 + mtl) * 2 + ot) * 272 + rr16 * 17 + m16];
        return s;
    };
    auto hPublish = [&](unsigned short* Hw) {
        __syncthreads();
        if (tid < 32) {
            int b = bg * 32 + tid;
            int chunk = ((b >> 4) * KS0 + (rb >> 2)) * 64 + ((b & 15) | ((rb & 3) << 4));
            cstore8((ull*)Hw + chunk * 2,     hstage[tid][0]);
            cstore8((ull*)Hw + chunk * 2 + 1, hstage[tid][1]);
        }
    };
    // P3 GEMM+cell from qa/qb (Wr2 resident); block-local h2/c2 update
    auto runP3 = [&](short8 (&qa)[8], short8 (&qb)[8], int t) {
        f32x4 a3[2][2];
        #pragma unroll
        for (int m = 0; m < 2; ++m)
            #pragma unroll
            for (int ot = 0; ot < 2; ++ot) a3[m][ot] = (f32x4){0.f, 0.f, 0.f, 0.f};
        #pragma unroll
        for (int kk = 0; kk < 8; ++kk) {
            #pragma unroll
            for (int ot = 0; ot < 2; ++ot) {
                a3[0][ot] = __builtin_amdgcn_mfma_f32_16x16x32_bf16(qa[kk], Wr2[ot][kk], a3[0][ot], 0, 0, 0);
                a3[1][ot] = __builtin_amdgcn_mfma_f32_16x16x32_bf16(qb[kk], Wr2[ot][kk], a3[1][ot], 0, 0, 0);
            }
        }
        redWrite(red1, a3);
        __syncthreads();
        float xo[8];
        #pragma unroll
        for (int d = 0; d < 8; ++d) xo[d] = h2x[bl * 9 + d];
        float g4[4];
        #pragma unroll
        for (int g = 0; g < 4; ++g) {
            float s = b2r[g] + redSum(red1, g);
            #pragma unroll
            for (int d = 0; d < 8; ++d) s += whh2r[g][d] * xo[d];
            g4[g] = s;
        }
        float cn = sigm(g4[1]) * c2r + sigm(g4[0]) * ftanh(g4[2]);
        c2r = cn;
        float hn2 = sigm(g4[3]) * ftanh(cn);
        __syncthreads();                // old-h2x reads done before overwrite
        h2x[bl * 9 + u] = hn2;
        // distributed pred store: each block owns 2 of the 256 (bl,u) slots
        if (t >= ENC - 1 && ((((bl << 3) | u) >> 1) == rb))
            pred[((bg * 32 + bl) * HOR + (t - (ENC - 1))) * DD + u] = hn2;
    };

    // qa/qb carry h1 fragments across the A barrier; zero = h1(-1)
    short8 qa[8], qb[8];
    {
        union { ull u[2]; short8 s; } z; z.u[0] = 0; z.u[1] = 0;
        #pragma unroll
        for (int kk = 0; kk < 8; ++kk) { qa[kk] = z.s; qb[kk] = z.s; }
    }
    __syncthreads();

    // ---- preamble: P1(0) (h0(-1)=0 -> GEMM term vanishes) ----
    {
        float xv[8];
        int b = bg * 32 + bl;
        #pragma unroll
        for (int d = 0; d < 8; ++d) xv[d] = inp[(b * TT + 0) * DD + d];
        float g4[4];
        #pragma unroll
        for (int g = 0; g < 4; ++g) {
            float s = b0r[g];
            #pragma unroll
            for (int d = 0; d < 8; ++d) s += wih0r[g][d] * xv[d];
            g4[g] = s;
        }
        c0r = sigm(g4[0]) * ftanh(g4[2]);
        float hn = sigm(g4[3]) * ftanh(c0r);
        ((unsigned short*)hstage)[bl * 8 + u] = f2bf(hn);
        hPublish(H0a);                               // h0(0)
    }
    gbar_arrive(dom, rb, ++ep);

    short8 pa[8], pb[8];

    for (int t = 0; t < NSTEP; ++t) {
        const int par = t & 1;
        const unsigned short* H0cur = par ? H0b : H0a;   // h0(t)
        unsigned short* H1w = par ? H1b : H1a;           // h1(t) dest
        unsigned short* H0nxt = par ? H0a : H0b;         // h0(t+1) dest
        const bool last = (t == NSTEP - 1);

        // ---- gap A: P2's h1(t-1) half from carried qa/qb ----
        f32x4 acc[2][2];
        #pragma unroll
        for (int m = 0; m < 2; ++m)
            #pragma unroll
            for (int ot = 0; ot < 2; ++ot) acc[m][ot] = (f32x4){0.f, 0.f, 0.f, 0.f};
        #pragma unroll
        for (int kk = 0; kk < 8; ++kk) {
            #pragma unroll
            for (int ot = 0; ot < 2; ++ot) {
                acc[0][ot] = __builtin_amdgcn_mfma_f32_16x16x32_bf16(qa[kk], Wr1h1[ot][kk], acc[0][ot], 0, 0, 0);
                acc[1][ot] = __builtin_amdgcn_mfma_f32_16x16x32_bf16(qb[kk], Wr1h1[ot][kk], acc[1][ot], 0, 0, 0);
            }
        }
        gbar_wait(dom, ep);                  // wait A: h0(t) visible

        // ================= window A =================
        {
            #pragma unroll
            for (int kk = 0; kk < 8; ++kk) {
                pa[kk] = cload(H0cur + (((bg * 2 + 0) * KS0 + 8 * wv + kk) * 64 + lane) * 8);
                pb[kk] = cload(H0cur + (((bg * 2 + 1) * KS0 + 8 * wv + kk) * 64 + lane) * 8);
            }
            #pragma unroll
            for (int kk = 0; kk < 8; ++kk) {
                #pragma unroll
                for (int ot = 0; ot < 2; ++ot) {
                    acc[0][ot] = __builtin_amdgcn_mfma_f32_16x16x32_bf16(pa[kk], Wr1h0[ot][kk], acc[0][ot], 0, 0, 0);
                    acc[1][ot] = __builtin_amdgcn_mfma_f32_16x16x32_bf16(pb[kk], Wr1h0[ot][kk], acc[1][ot], 0, 0, 0);
                }
            }
            redWrite(red1, acc);
            __syncthreads();
            float g4[4];
            #pragma unroll
            for (int g = 0; g < 4; ++g) g4[g] = b1r[g] + redSum(red1, g);
            c1r = sigm(g4[1]) * c1r + sigm(g4[0]) * ftanh(g4[2]);
            float hn = sigm(g4[3]) * ftanh(c1r);
            ((unsigned short*)hstage)[bl * 8 + u] = f2bf(hn);
            hPublish(H1w);                               // h1(t)
        }
        gbar_arrive(dom, rb, ++ep);          // arrive B

        // ---- gap B: P1(t+1) GEMM on pa/pb (h0(t)) ----
        if (!last) {
            f32x4 a1[2][2];
            #pragma unroll
            for (int m = 0; m < 2; ++m)
                #pragma unroll
                for (int ot = 0; ot < 2; ++ot) a1[m][ot] = (f32x4){0.f, 0.f, 0.f, 0.f};
            #pragma unroll
            for (int kk = 0; kk < 8; ++kk) {
                #pragma unroll
                for (int ot = 0; ot < 2; ++ot) {
                    a1[0][ot] = __builtin_amdgcn_mfma_f32_16x16x32_bf16(pa[kk], Wr0[ot][kk], a1[0][ot], 0, 0, 0);
                    a1[1][ot] = __builtin_amdgcn_mfma_f32_16x16x32_bf16(pb[kk], Wr0[ot][kk], a1[1][ot], 0, 0, 0);
                }
            }
            redWrite(red2, a1);
        }
        gbar_wait(dom, ep);                  // wait B: h1(t) visible

        // ================= window B =================
        {
            #pragma unroll
            for (int kk = 0; kk < 8; ++kk) {
                qa[kk] = cload(H1w + (((bg * 2 + 0) * KS0 + 8 * wv + kk) * 64 + lane) * 8);
                qb[kk] = cload(H1w + (((bg * 2 + 1) * KS0 + 8 * wv + kk) * 64 + lane) * 8);
            }
            const int tt = t + 1;
            if (!last && tt < ENC) {
                // ---- encoder fast path: P1 cell first (x from inp, no h2 dep)
                float g1[4];
                int b = bg * 32 + bl;
                #pragma unroll
                for (int g = 0; g < 4; ++g) {
                    float s = b0r[g] + redSum(red2, g);
                    #pragma unroll
                    for (int d = 0; d < 8; ++d) s += wih0r[g][d] * inp[(b * TT + tt) * DD + d];
                    g1[g] = s;
                }
                c0r = sigm(g1[1]) * c0r + sigm(g1[0]) * ftanh(g1[2]);
                float hn0 = sigm(g1[3]) * ftanh(c0r);
                ((unsigned short*)hstage)[bl * 8 + u] = f2bf(hn0);
                hPublish(H0nxt);                          // h0(t+1)
                gbar_arrive(dom, rb, ++ep);               // arrive A EARLY
                runP3(qa, qb, t);            // c2/h2 chain in the arrive-A gap
            } else {
                // ---- decode path ----
                float g1p[4];
                if (!last) {
                    #pragma unroll
                    for (int g = 0; g < 4; ++g) g1p[g] = b0r[g] + redSum(red2, g);
                }
                runP3(qa, qb, t);
                if (!last) {
                    __syncthreads();        // h2x(t) visible
                    float xv[8];
                    #pragma unroll
                    for (int d = 0; d < 8; ++d) xv[d] = h2x[bl * 9 + d];
                    float g1[4];
                    #pragma unroll
                    for (int g = 0; g < 4; ++g) {
                        float s = g1p[g];
                        #pragma unroll
                        for (int d = 0; d < 8; ++d) s += wih0r[g][d] * xv[d];
                        g1[g] = s;
                    }
                    c0r = sigm(g1[1]) * c0r + sigm(g1[0]) * ftanh(g1[2]);
                    float hn0 = sigm(g1[3]) * ftanh(c0r);
                    ((unsigned short*)hstage)[bl * 8 + u] = f2bf(hn0);
                    hPublish(H0nxt);                      // h0(t+1)
                    gbar_arrive(dom, rb, ++ep);           // arrive A
                }
            }
        }
    }
}

// ---------------- host ----------------

extern "C" void kernel_launch(void* const* d_in, const int* in_sizes, int n_in,
                              void* d_out, int out_size, void* d_ws, size_t ws_size,
                              hipStream_t stream)
{
    const float* inp  = (const float*)d_in[0];
    const float* wih0 = (const float*)d_in[1];
    const float* whh0 = (const float*)d_in[2];
    const float* b0v  = (const float*)d_in[3];
    const float* wih1 = (const float*)d_in[4];
    const float* whh1 = (const float*)d_in[5];
    const float* b1v  = (const float*)d_in[6];
    const float* wih2 = (const float*)d_in[7];
    const float* whh2 = (const float*)d_in[8];
    const float* b2v  = (const float*)d_in[9];
    float* out = (float*)d_out;   // pred[172032] | y[172032] | loss[8]

    char* base = (char*)d_ws;
    size_t off = 0;
    auto carve = [&](size_t bytes) -> void* {
        void* p = base + off;
        off += (bytes + 255) & ~((size_t)255);
        return p;
    };
    unsigned short* Wp0 = (unsigned short*)carve((size_t)128 * 2 * KS0 * 64 * 8 * 2);
    unsigned short* Wp1 = (unsigned short*)carve((size_t)128 * 2 * KS1 * 64 * 8 * 2);
    unsigned short* Wp2 = (unsigned short*)carve((size_t)2 * KS0 * 64 * 8 * 2);
    size_t state_off = off;
    unsigned short* H0a = (unsigned short*)carve(B64 * H * 2);
    unsigned short* H0b = (unsigned short*)carve(B64 * H * 2);
    unsigned short* H1a = (unsigned short*)carve(B64 * H * 2);
    unsigned short* H1b = (unsigned short*)carve(B64 * H * 2);
    unsigned* bar = (unsigned*)carve(2 * 8192 * 4);   // 2 domains x 32KB
    size_t state_bytes = off - state_off;
    if (off > ws_size) return;

    zero_k<<<64, 256, 0, stream>>>((unsigned int*)(base + state_off), (int)(state_bytes / 4));
    pack0_k<<<2048, 256, 0, stream>>>(whh0, Wp0);
    pack1_k<<<4096, 256, 0, stream>>>(wih1, whh1, Wp1);
    pack2_k<<<32, 256, 0, stream>>>(wih2, Wp2);
    copy_y_k<<<672, 256, 0, stream>>>(inp, out + 172032);

    persist_k<<<NBLK, 256, 0, stream>>>(Wp0, Wp1, Wp2, wih0, b0v, b1v, whh2, b2v,
                                        inp, H0a, H0b, H1a, H1b, bar, out);

    loss_k<<<1, 256, 0, stream>>>(out, out + 172032, out + 344064);
}